// Round 6
// baseline (340.876 us; speedup 1.0000x reference)
//
#include <hip/hip_runtime.h>
#include <hip/hip_bf16.h>

#define D_MODEL 384
#define N_HEAD  6
#define HEAD    64
#define T_LEN   256
#define BATCH   128
#define MROWS   (BATCH * T_LEN)   // 32768
#define FF      1536

typedef __bf16 bf16x8 __attribute__((ext_vector_type(8)));
typedef float  f32x4  __attribute__((ext_vector_type(4)));
typedef unsigned short us8 __attribute__((ext_vector_type(8)));
typedef unsigned short us4 __attribute__((ext_vector_type(4)));
using bf16 = __hip_bfloat16;

__device__ inline f32x4 mfma16(bf16x8 a, bf16x8 b, f32x4 c) {
    return __builtin_amdgcn_mfma_f32_16x16x32_bf16(a, b, c, 0, 0, 0);
}

// async global->LDS, 16B per lane; LDS dest = wave-uniform base + lane*16
#define GLOAD_LDS16(g, l) __builtin_amdgcn_global_load_lds( \
    (const __attribute__((address_space(1))) unsigned int*)(g), \
    (__attribute__((address_space(3))) unsigned int*)(l), 16, 0, 0)

// ---------------- weight prep: cast to bf16, transpose to [N][K] ----------------
__global__ __launch_bounds__(256) void prep_w(
    const float* __restrict__ Wq, const float* __restrict__ Wk, const float* __restrict__ Wv,
    const float* __restrict__ Wp, const float* __restrict__ W1, const float* __restrict__ W2,
    bf16* __restrict__ Wqkv_t, bf16* __restrict__ Wp_t,
    bf16* __restrict__ W1_t,   bf16* __restrict__ W2_t)
{
    int i = blockIdx.x * 256 + threadIdx.x;
    if (i < 1152 * 384) {
        int cc = i / 384, d = i - cc * 384;
        const float* src = cc < 384 ? Wq : (cc < 768 ? Wk : Wv);
        int c = cc < 384 ? cc : (cc < 768 ? cc - 384 : cc - 768);
        int h = c >> 6, e = c & 63;
        Wqkv_t[i] = __float2bfloat16(src[(h * 384 + d) * 64 + e]);
    }
    if (i < 384 * 384) {
        int o = i / 384, d = i - o * 384;
        Wp_t[i] = __float2bfloat16(Wp[d * 384 + o]);
    }
    if (i < 1536 * 384) {
        int o = i / 384, d = i - o * 384;          // W1_t[o][d]
        W1_t[i] = __float2bfloat16(W1[d * 1536 + o]);
        int o2 = i / 1536, d2 = i - o2 * 1536;     // W2_t[o2][d2]
        W2_t[i] = __float2bfloat16(W2[d2 * 384 + o2]);
    }
}

// ---------------- layernorm: one wave per row of 384 ----------------
__global__ __launch_bounds__(256) void ln_k(
    const float* __restrict__ xin, const float* __restrict__ gg,
    const float* __restrict__ bb, bf16* __restrict__ outb)
{
    int wid  = blockIdx.x * 4 + (threadIdx.x >> 6);
    int lane = threadIdx.x & 63;
    const float* xr = xin + (size_t)wid * 384;
    float v[6]; float s = 0.f;
#pragma unroll
    for (int i = 0; i < 6; ++i) { v[i] = xr[lane + i * 64]; s += v[i]; }
#pragma unroll
    for (int mk = 1; mk < 64; mk <<= 1) s += __shfl_xor(s, mk);
    float mu = s * (1.f / 384.f);
    float vs = 0.f;
#pragma unroll
    for (int i = 0; i < 6; ++i) { float d = v[i] - mu; vs += d * d; }
#pragma unroll
    for (int mk = 1; mk < 64; mk <<= 1) vs += __shfl_xor(vs, mk);
    float rs = rsqrtf(vs * (1.f / 384.f) + 1e-5f);
    bf16* orow = outb + (size_t)wid * 384;
#pragma unroll
    for (int i = 0; i < 6; ++i) {
        int c = lane + i * 64;
        orow[c] = __float2bfloat16((v[i] - mu) * rs * gg[c] + bb[c]);
    }
}

// -------- v slice of qkv[m][1152] -> vT[b,h,e,t] coalesced LDS transpose -------
__global__ __launch_bounds__(256) void tr_v(
    const bf16* __restrict__ qkv, bf16* __restrict__ vT)
{
    __shared__ bf16 L[256][68];   // +4 pad
    int bh = blockIdx.x;
    int b = bh / N_HEAD, h = bh - b * N_HEAD;
    int tid = threadIdx.x;
    const bf16* src = qkv + (size_t)(b * T_LEN + tid) * 1152 + 768 + h * 64;
#pragma unroll
    for (int c = 0; c < 8; ++c)
        *(us8*)&L[tid][c * 8] = *(const us8*)&src[c * 8];
    __syncthreads();
    bf16* dst = vT + (size_t)bh * HEAD * T_LEN;
#pragma unroll
    for (int i = 0; i < 8; ++i) {
        int idx = tid + i * 256;            // 0..2047
        int e = idx >> 5, tc = (idx & 31) * 8;
        bf16x8 pk;
#pragma unroll
        for (int j = 0; j < 8; ++j) pk[j] = *(__bf16*)&L[tc + j][e];
        *(bf16x8*)&dst[(size_t)e * T_LEN + tc] = pk;
    }
}

// ======== 8-wave pipelined GEMM, BM=128 BN=192 BK=64, 2 blocks/CU ========
enum { EPI_QKV = 0, EPI_PROJ = 1, EPI_FFN1 = 2, EPI_FFN2 = 3 };

template<int EPI, int K, int NTN>
__global__ __launch_bounds__(512, 4) void gemm8(
    const bf16* __restrict__ A, const bf16* __restrict__ Bt,
    const float* __restrict__ bias, const float* __restrict__ resid,
    float* __restrict__ outf, bf16* __restrict__ outq, bf16* __restrict__ outb)
{
    extern __shared__ char smem[];
    bf16* Albase = (bf16*)smem;                  // [2][128][64] elems
    bf16* Blbase = (bf16*)(smem + 32768);        // [2][192][64] elems
    constexpr int NT = K / 64;
    constexpr int nwg = (MROWS / 128) * NTN;     // multiple of 8
    int bid = blockIdx.x;
    int wg = (bid & 7) * (nwg >> 3) + (bid >> 3);   // bijective XCD chunking
    int mt = wg / NTN, nt = wg - mt * NTN;          // nt fastest within chunk
    int m0 = mt * 128, n0 = nt * 192;
    int tid = threadIdx.x, lane = tid & 63, w = tid >> 6;
    int r = lane & 15, g = lane >> 4;
    int lr8 = lane >> 3, l7 = lane & 7;
    int csw = (l7 ^ lr8) << 3;      // pre-swizzled source col offset (elements)
    int wm = (w & 3) * 32, wn = (w >> 2) * 96;   // 4 wave-rows x 2 wave-cols
    int sb = g ^ l7;                // read slot base (16B slots)

    const bf16* Ag = A  + (size_t)(m0 + w * 16 + lr8) * K + csw;
    const bf16* Bg = Bt + (size_t)(n0 + w * 24 + lr8) * K + csw;
    const int AL0 = w * 16 * 64;    // wave-uniform LDS element offsets
    const int BL0 = w * 24 * 64;

#define STAGE(tt, bb) do { \
    const bf16* a_ = Ag + (tt) * 64; \
    bf16* al_ = Albase + (bb) * 8192 + AL0; \
    _Pragma("unroll") for (int q_ = 0; q_ < 2; ++q_) \
        GLOAD_LDS16(a_ + (size_t)q_ * 8 * K, al_ + q_ * 8 * 64); \
    const bf16* b_ = Bg + (tt) * 64; \
    bf16* bl_ = Blbase + (bb) * 12288 + BL0; \
    _Pragma("unroll") for (int q_ = 0; q_ < 3; ++q_) \
        GLOAD_LDS16(b_ + (size_t)q_ * 8 * K, bl_ + q_ * 8 * 64); \
} while (0)

    f32x4 acc[2][6];
#pragma unroll
    for (int i = 0; i < 2; ++i)
#pragma unroll
        for (int j = 0; j < 6; ++j) acc[i][j] = (f32x4){0.f, 0.f, 0.f, 0.f};

    STAGE(0, 0);
    STAGE(1, 1);

#define ITER(tt, VMS, DOSTAGE) do { \
    int bb_ = (tt) & 1; \
    asm volatile("s_waitcnt vmcnt(" VMS ")" ::: "memory"); \
    __builtin_amdgcn_s_barrier(); \
    __builtin_amdgcn_sched_barrier(0); \
    const bf16* Ar_ = Albase + bb_ * 8192; \
    const bf16* Br_ = Blbase + bb_ * 12288; \
    _Pragma("unroll") for (int kk = 0; kk < 2; ++kk) { \
        int so_ = (sb ^ (kk * 4)) << 3; \
        bf16x8 af0 = *(const bf16x8*)&Ar_[(wm + r) * 64 + so_]; \
        bf16x8 af1 = *(const bf16x8*)&Ar_[(wm + 16 + r) * 64 + so_]; \
        bf16x8 bfv[6]; \
        _Pragma("unroll") for (int ni = 0; ni < 6; ++ni) \
            bfv[ni] = *(const bf16x8*)&Br_[(wn + ni * 16 + r) * 64 + so_]; \
        asm volatile("s_waitcnt lgkmcnt(0)" ::: "memory"); \
        __builtin_amdgcn_sched_barrier(0); \
        __builtin_amdgcn_s_setprio(1); \
        _Pragma("unroll") for (int ni = 0; ni < 6; ++ni) { \
            acc[0][ni] = mfma16(bfv[ni], af0, acc[0][ni]); \
            acc[1][ni] = mfma16(bfv[ni], af1, acc[1][ni]); \
        } \
        __builtin_amdgcn_s_setprio(0); \
    } \
    __builtin_amdgcn_s_barrier(); \
    if (DOSTAGE) STAGE((tt) + 2, bb_); \
} while (0)

#pragma unroll 1
    for (int t = 0; t < NT - 2; ++t) ITER(t, "5", true);
    ITER(NT - 2, "5", false);
    ITER(NT - 1, "0", false);
#undef ITER
#undef STAGE

    // epilogue (swapped layout): m = wm+mi*16+r (per lane), n = wn+ni*16+g*4+j
#pragma unroll
    for (int mi = 0; mi < 2; ++mi) {
        size_t m = m0 + wm + mi * 16 + r;
#pragma unroll
        for (int ni = 0; ni < 6; ++ni) {
            int nb = n0 + wn + ni * 16 + (g << 2);
            f32x4 a = acc[mi][ni];
            if constexpr (EPI == EPI_QKV) {
                us4 u;
#pragma unroll
                for (int j = 0; j < 4; ++j) {
                    __bf16 hb = (__bf16)a[j];
                    u[j] = __builtin_bit_cast(unsigned short, hb);
                }
                *(us4*)&outq[m * 1152 + nb] = u;
            } else if constexpr (EPI == EPI_FFN1) {
                f32x4 b4 = *(const f32x4*)&bias[nb];
                us4 u;
#pragma unroll
                for (int j = 0; j < 4; ++j) {
                    float z = a[j] + b4[j]; z = z > 0.f ? z : 0.f;
                    __bf16 hb = (__bf16)z;
                    u[j] = __builtin_bit_cast(unsigned short, hb);
                }
                *(us4*)&outb[m * FF + nb] = u;
            } else {
                f32x4 b4 = *(const f32x4*)&bias[nb];
                f32x4 rv = *(const f32x4*)&resid[m * 384 + nb];
                f32x4 o;
#pragma unroll
                for (int j = 0; j < 4; ++j) o[j] = rv[j] + a[j] + b4[j];
                *(f32x4*)&outf[m * 384 + nb] = o;
            }
        }
    }
}

// -------- barrier-free causal attention: K/V direct from L2, P-only LDS --------
__global__ __launch_bounds__(256) void attn_k(
    const bf16* __restrict__ qkv, const bf16* __restrict__ vT,
    bf16* __restrict__ att)
{
    __shared__ bf16 Psm[4][16][68];   // stride 136B -> conflict-free b128 reads
    int bid = blockIdx.x;
    // XCD chunking: all 4 q-tiles of a head land on one XCD (K/V L2 locality)
    int wg = (bid & 7) * (3072 >> 3) + (bid >> 3);
    int qt = wg & 3, bh = wg >> 2;
    int b = bh / N_HEAD, h = bh - b * N_HEAD;
    int q0 = qt * 64;
    int tid = threadIdx.x, lane = tid & 63, w = tid >> 6;
    int r = lane & 15, g = lane >> 4, ko = g << 3;

    const bf16* qbase = qkv + (size_t)b * T_LEN * 1152 + h * 64;
    const bf16* kbase = qbase + 384;
    const bf16* vbase = vT + (size_t)bh * HEAD * T_LEN;

    bf16x8 qf[2];
    qf[0] = *(const bf16x8*)&qbase[(size_t)(q0 + w * 16 + r) * 1152 + ko];
    qf[1] = *(const bf16x8*)&qbase[(size_t)(q0 + w * 16 + r) * 1152 + ko + 32];

    f32x4 o[4];
#pragma unroll
    for (int i = 0; i < 4; ++i) o[i] = (f32x4){0.f, 0.f, 0.f, 0.f};
    float mrow[4], lrow[4];
#pragma unroll
    for (int j = 0; j < 4; ++j) { mrow[j] = -3.0e38f; lrow[j] = 0.f; }

    for (int st = 0; st <= qt; ++st) {
        int s0 = st * 64;
        // QK^T: K fragments straight from global (L2-resident)
        f32x4 s[4];
#pragma unroll
        for (int i = 0; i < 4; ++i) s[i] = (f32x4){0.f, 0.f, 0.f, 0.f};
#pragma unroll
        for (int kk = 0; kk < 2; ++kk) {
#pragma unroll
            for (int ni = 0; ni < 4; ++ni) {
                bf16x8 kf = *(const bf16x8*)&kbase[(size_t)(s0 + ni * 16 + r) * 1152 + kk * 32 + ko];
                s[ni] = mfma16(qf[kk], kf, s[ni]);
            }
        }
        // scale + causal mask + per-row (16-lane-group) online softmax
        int qrow = q0 + w * 16 + (g << 2);
        float tmax[4], fsc[4], tsum[4];
#pragma unroll
        for (int j = 0; j < 4; ++j) {
            float mx = -3.0e38f;
#pragma unroll
            for (int ni = 0; ni < 4; ++ni) {
                int col = s0 + ni * 16 + r;
                float sv = (col <= qrow + j) ? s[ni][j] * 0.125f : -3.0e38f;
                s[ni][j] = sv;
                mx = fmaxf(mx, sv);
            }
            tmax[j] = mx;
        }
#pragma unroll
        for (int mk = 1; mk < 16; mk <<= 1)
#pragma unroll
            for (int j = 0; j < 4; ++j) tmax[j] = fmaxf(tmax[j], __shfl_xor(tmax[j], mk));
#pragma unroll
        for (int j = 0; j < 4; ++j) {
            float mnew = fmaxf(mrow[j], tmax[j]);
            fsc[j] = __expf(mrow[j] - mnew);
            mrow[j] = mnew;
            float ss = 0.f;
#pragma unroll
            for (int ni = 0; ni < 4; ++ni) {
                float p = __expf(s[ni][j] - mnew);
                s[ni][j] = p; ss += p;
            }
            tsum[j] = ss;
        }
#pragma unroll
        for (int mk = 1; mk < 16; mk <<= 1)
#pragma unroll
            for (int j = 0; j < 4; ++j) tsum[j] += __shfl_xor(tsum[j], mk);
#pragma unroll
        for (int j = 0; j < 4; ++j) lrow[j] = lrow[j] * fsc[j] + tsum[j];
#pragma unroll
        for (int ni = 0; ni < 4; ++ni)
#pragma unroll
            for (int j = 0; j < 4; ++j) o[ni][j] *= fsc[j];
        // P -> per-wave LDS (no cross-wave sharing, no barrier), then PV
#pragma unroll
        for (int ni = 0; ni < 4; ++ni)
#pragma unroll
            for (int j = 0; j < 4; ++j)
                Psm[w][(g << 2) + j][ni * 16 + r] = __float2bfloat16(s[ni][j]);
#pragma unroll
        for (int kk = 0; kk < 2; ++kk) {
            bf16x8 pf = *(const bf16x8*)&Psm[w][r][kk * 32 + ko];
#pragma unroll
            for (int ni = 0; ni < 4; ++ni) {
                bf16x8 vf = *(const bf16x8*)&vbase[(size_t)(ni * 16 + r) * T_LEN + s0 + kk * 32 + ko];
                o[ni] = mfma16(pf, vf, o[ni]);
            }
        }
    }

#pragma unroll
    for (int ni = 0; ni < 4; ++ni)
#pragma unroll
        for (int j = 0; j < 4; ++j) {
            int t = q0 + w * 16 + (g << 2) + j;
            int e = h * HEAD + ni * 16 + r;
            att[((size_t)b * T_LEN + t) * D_MODEL + e] = __float2bfloat16(o[ni][j] / lrow[j]);
        }
}

// ---------------- launch ----------------
#define GEMM_SMEM 81920

extern "C" void kernel_launch(void* const* d_in, const int* in_sizes, int n_in,
                              void* d_out, int out_size, void* d_ws, size_t ws_size,
                              hipStream_t stream)
{
    const float* x   = (const float*)d_in[0];
    const float* Wq  = (const float*)d_in[1];
    const float* Wk  = (const float*)d_in[2];
    const float* Wv  = (const float*)d_in[3];
    const float* Wp  = (const float*)d_in[4];
    const float* bp  = (const float*)d_in[5];
    const float* W1  = (const float*)d_in[6];
    const float* b1  = (const float*)d_in[7];
    const float* W2  = (const float*)d_in[8];
    const float* b2  = (const float*)d_in[9];
    const float* g1  = (const float*)d_in[10];
    const float* be1 = (const float*)d_in[11];
    const float* g2  = (const float*)d_in[12];
    const float* be2 = (const float*)d_in[13];
    float* out = (float*)d_out;

    char* ws = (char*)d_ws;
    size_t off = 0;
    auto alloc = [&](size_t bytes) { void* p = ws + off; off += (bytes + 255) & ~(size_t)255; return p; };
    bf16* Wqkv_t = (bf16*)alloc((size_t)1152 * 384 * 2);
    bf16* Wp_t   = (bf16*)alloc((size_t)384 * 384 * 2);
    bf16* W1_t   = (bf16*)alloc((size_t)1536 * 384 * 2);
    bf16* W2_t   = (bf16*)alloc((size_t)384 * 1536 * 2);
    bf16* h      = (bf16*)alloc((size_t)MROWS * 384 * 2);   // ln1 out; vT alias; ln2 out
    bf16* qkv    = (bf16*)alloc((size_t)MROWS * 1152 * 2);  // merged q|k|v
    bf16* attb   = (bf16*)alloc((size_t)MROWS * 384 * 2);
    float* x1    = (float*)alloc((size_t)MROWS * 384 * 4);
    bf16* vTb    = h;             // alias: h (ln1 out) dead after QKV gemm
    bf16* ff1    = qkv;           // alias: qkv+attb dead by FFN1; spans both

    hipFuncSetAttribute(reinterpret_cast<const void*>(&gemm8<EPI_QKV, 384, 6>),
                        hipFuncAttributeMaxDynamicSharedMemorySize, GEMM_SMEM);
    hipFuncSetAttribute(reinterpret_cast<const void*>(&gemm8<EPI_PROJ, 384, 2>),
                        hipFuncAttributeMaxDynamicSharedMemorySize, GEMM_SMEM);
    hipFuncSetAttribute(reinterpret_cast<const void*>(&gemm8<EPI_FFN1, 384, 8>),
                        hipFuncAttributeMaxDynamicSharedMemorySize, GEMM_SMEM);
    hipFuncSetAttribute(reinterpret_cast<const void*>(&gemm8<EPI_FFN2, 1536, 2>),
                        hipFuncAttributeMaxDynamicSharedMemorySize, GEMM_SMEM);

    prep_w<<<2304, 256, 0, stream>>>(Wq, Wk, Wv, Wp, W1, W2, Wqkv_t, Wp_t, W1_t, W2_t);
    ln_k<<<MROWS / 4, 256, 0, stream>>>(x, g1, be1, h);
    gemm8<EPI_QKV, 384, 6><<<1536, 512, GEMM_SMEM, stream>>>(
        h, Wqkv_t, nullptr, nullptr, nullptr, qkv, nullptr);
    tr_v<<<BATCH * N_HEAD, 256, 0, stream>>>(qkv, vTb);
    attn_k<<<BATCH * N_HEAD * 4, 256, 0, stream>>>(qkv, vTb, attb);
    gemm8<EPI_PROJ, 384, 2><<<512, 512, GEMM_SMEM, stream>>>(
        attb, Wp_t, bp, x, x1, nullptr, nullptr);
    ln_k<<<MROWS / 4, 256, 0, stream>>>(x1, g2, be2, h);
    gemm8<EPI_FFN1, 384, 8><<<2048, 512, GEMM_SMEM, stream>>>(
        h, W1_t, b1, nullptr, nullptr, nullptr, ff1);
    gemm8<EPI_FFN2, 1536, 2><<<512, 512, GEMM_SMEM, stream>>>(
        ff1, W2_t, b2, x1, out, nullptr, nullptr);
}

// Round 7
// 296.438 us; speedup vs baseline: 1.1499x; 1.1499x over previous
//
#include <hip/hip_runtime.h>
#include <hip/hip_bf16.h>

#define D_MODEL 384
#define N_HEAD  6
#define HEAD    64
#define T_LEN   256
#define BATCH   128
#define MROWS   (BATCH * T_LEN)   // 32768
#define FF      1536

typedef __bf16 bf16x8 __attribute__((ext_vector_type(8)));
typedef float  f32x4  __attribute__((ext_vector_type(4)));
typedef unsigned short us8 __attribute__((ext_vector_type(8)));
typedef unsigned short us4 __attribute__((ext_vector_type(4)));
using bf16 = __hip_bfloat16;

__device__ inline f32x4 mfma16(bf16x8 a, bf16x8 b, f32x4 c) {
    return __builtin_amdgcn_mfma_f32_16x16x32_bf16(a, b, c, 0, 0, 0);
}

// async global->LDS, 16B per lane; LDS dest = wave-uniform base + lane*16
#define GLOAD_LDS16(g, l) __builtin_amdgcn_global_load_lds( \
    (const __attribute__((address_space(1))) unsigned int*)(g), \
    (__attribute__((address_space(3))) unsigned int*)(l), 16, 0, 0)

// ---------------- weight prep: cast to bf16, transpose to [N][K] ----------------
__global__ __launch_bounds__(256) void prep_w(
    const float* __restrict__ Wq, const float* __restrict__ Wk, const float* __restrict__ Wv,
    const float* __restrict__ Wp, const float* __restrict__ W1, const float* __restrict__ W2,
    bf16* __restrict__ Wqkv_t, bf16* __restrict__ Wp_t,
    bf16* __restrict__ W1_t,   bf16* __restrict__ W2_t)
{
    int i = blockIdx.x * 256 + threadIdx.x;
    if (i < 1152 * 384) {
        int cc = i / 384, d = i - cc * 384;
        const float* src = cc < 384 ? Wq : (cc < 768 ? Wk : Wv);
        int c = cc < 384 ? cc : (cc < 768 ? cc - 384 : cc - 768);
        int h = c >> 6, e = c & 63;
        Wqkv_t[i] = __float2bfloat16(src[(h * 384 + d) * 64 + e]);
    }
    if (i < 384 * 384) {
        int o = i / 384, d = i - o * 384;
        Wp_t[i] = __float2bfloat16(Wp[d * 384 + o]);
    }
    if (i < 1536 * 384) {
        int o = i / 384, d = i - o * 384;          // W1_t[o][d]
        W1_t[i] = __float2bfloat16(W1[d * 1536 + o]);
        int o2 = i / 1536, d2 = i - o2 * 1536;     // W2_t[o2][d2]
        W2_t[i] = __float2bfloat16(W2[d2 * 384 + o2]);
    }
}

// ---------------- layernorm: one wave per row of 384 ----------------
__global__ __launch_bounds__(256) void ln_k(
    const float* __restrict__ xin, const float* __restrict__ gg,
    const float* __restrict__ bb, bf16* __restrict__ outb)
{
    int wid  = blockIdx.x * 4 + (threadIdx.x >> 6);
    int lane = threadIdx.x & 63;
    const float* xr = xin + (size_t)wid * 384;
    float v[6]; float s = 0.f;
#pragma unroll
    for (int i = 0; i < 6; ++i) { v[i] = xr[lane + i * 64]; s += v[i]; }
#pragma unroll
    for (int mk = 1; mk < 64; mk <<= 1) s += __shfl_xor(s, mk);
    float mu = s * (1.f / 384.f);
    float vs = 0.f;
#pragma unroll
    for (int i = 0; i < 6; ++i) { float d = v[i] - mu; vs += d * d; }
#pragma unroll
    for (int mk = 1; mk < 64; mk <<= 1) vs += __shfl_xor(vs, mk);
    float rs = rsqrtf(vs * (1.f / 384.f) + 1e-5f);
    bf16* orow = outb + (size_t)wid * 384;
#pragma unroll
    for (int i = 0; i < 6; ++i) {
        int c = lane + i * 64;
        orow[c] = __float2bfloat16((v[i] - mu) * rs * gg[c] + bb[c]);
    }
}

// -------- v slice of qkv[m][1152] -> vT[b,h,e,t] coalesced LDS transpose -------
__global__ __launch_bounds__(256) void tr_v(
    const bf16* __restrict__ qkv, bf16* __restrict__ vT)
{
    __shared__ bf16 L[256][68];   // +4 pad
    int bh = blockIdx.x;
    int b = bh / N_HEAD, h = bh - b * N_HEAD;
    int tid = threadIdx.x;
    const bf16* src = qkv + (size_t)(b * T_LEN + tid) * 1152 + 768 + h * 64;
#pragma unroll
    for (int c = 0; c < 8; ++c)
        *(us8*)&L[tid][c * 8] = *(const us8*)&src[c * 8];
    __syncthreads();
    bf16* dst = vT + (size_t)bh * HEAD * T_LEN;
#pragma unroll
    for (int i = 0; i < 8; ++i) {
        int idx = tid + i * 256;            // 0..2047
        int e = idx >> 5, tc = (idx & 31) * 8;
        bf16x8 pk;
#pragma unroll
        for (int j = 0; j < 8; ++j) pk[j] = *(__bf16*)&L[tc + j][e];
        *(bf16x8*)&dst[(size_t)e * T_LEN + tc] = pk;
    }
}

// ======== 8-wave pipelined GEMM, BM=128 BN=192 BK=64, 2 blocks/CU ========
enum { EPI_QKV = 0, EPI_PROJ = 1, EPI_FFN1 = 2, EPI_FFN2 = 3 };

template<int EPI, int K, int NTN>
__global__ __launch_bounds__(512, 4) void gemm8(
    const bf16* __restrict__ A, const bf16* __restrict__ Bt,
    const float* __restrict__ bias, const float* __restrict__ resid,
    float* __restrict__ outf, bf16* __restrict__ outq, bf16* __restrict__ outb)
{
    extern __shared__ char smem[];
    bf16* Albase = (bf16*)smem;                  // [2][128][64] elems
    bf16* Blbase = (bf16*)(smem + 32768);        // [2][192][64] elems
    constexpr int NT = K / 64;
    constexpr int nwg = (MROWS / 128) * NTN;     // multiple of 8
    int bid = blockIdx.x;
    int wg = (bid & 7) * (nwg >> 3) + (bid >> 3);   // bijective XCD chunking
    int mt = wg / NTN, nt = wg - mt * NTN;          // nt fastest within chunk
    int m0 = mt * 128, n0 = nt * 192;
    int tid = threadIdx.x, lane = tid & 63, w = tid >> 6;
    int r = lane & 15, g = lane >> 4;
    int lr8 = lane >> 3, l7 = lane & 7;
    int csw = (l7 ^ lr8) << 3;      // pre-swizzled source col offset (elements)
    int wm = (w & 3) * 32, wn = (w >> 2) * 96;   // 4 wave-rows x 2 wave-cols
    int sb = g ^ l7;                // read slot base (16B slots)

    const bf16* Ag = A  + (size_t)(m0 + w * 16 + lr8) * K + csw;
    const bf16* Bg = Bt + (size_t)(n0 + w * 24 + lr8) * K + csw;
    const int AL0 = w * 16 * 64;    // wave-uniform LDS element offsets
    const int BL0 = w * 24 * 64;

#define STAGE(tt, bb) do { \
    const bf16* a_ = Ag + (tt) * 64; \
    bf16* al_ = Albase + (bb) * 8192 + AL0; \
    _Pragma("unroll") for (int q_ = 0; q_ < 2; ++q_) \
        GLOAD_LDS16(a_ + (size_t)q_ * 8 * K, al_ + q_ * 8 * 64); \
    const bf16* b_ = Bg + (tt) * 64; \
    bf16* bl_ = Blbase + (bb) * 12288 + BL0; \
    _Pragma("unroll") for (int q_ = 0; q_ < 3; ++q_) \
        GLOAD_LDS16(b_ + (size_t)q_ * 8 * K, bl_ + q_ * 8 * 64); \
} while (0)

    f32x4 acc[2][6];
#pragma unroll
    for (int i = 0; i < 2; ++i)
#pragma unroll
        for (int j = 0; j < 6; ++j) acc[i][j] = (f32x4){0.f, 0.f, 0.f, 0.f};

    STAGE(0, 0);
    STAGE(1, 1);

#define ITER(tt, VMS, DOSTAGE) do { \
    int bb_ = (tt) & 1; \
    asm volatile("s_waitcnt vmcnt(" VMS ")" ::: "memory"); \
    __builtin_amdgcn_s_barrier(); \
    __builtin_amdgcn_sched_barrier(0); \
    const bf16* Ar_ = Albase + bb_ * 8192; \
    const bf16* Br_ = Blbase + bb_ * 12288; \
    _Pragma("unroll") for (int kk = 0; kk < 2; ++kk) { \
        int so_ = (sb ^ (kk * 4)) << 3; \
        bf16x8 af0 = *(const bf16x8*)&Ar_[(wm + r) * 64 + so_]; \
        bf16x8 af1 = *(const bf16x8*)&Ar_[(wm + 16 + r) * 64 + so_]; \
        bf16x8 bfv[6]; \
        _Pragma("unroll") for (int ni = 0; ni < 6; ++ni) \
            bfv[ni] = *(const bf16x8*)&Br_[(wn + ni * 16 + r) * 64 + so_]; \
        asm volatile("s_waitcnt lgkmcnt(0)" ::: "memory"); \
        __builtin_amdgcn_sched_barrier(0); \
        __builtin_amdgcn_s_setprio(1); \
        _Pragma("unroll") for (int ni = 0; ni < 6; ++ni) { \
            acc[0][ni] = mfma16(bfv[ni], af0, acc[0][ni]); \
            acc[1][ni] = mfma16(bfv[ni], af1, acc[1][ni]); \
        } \
        __builtin_amdgcn_s_setprio(0); \
    } \
    __builtin_amdgcn_s_barrier(); \
    if (DOSTAGE) STAGE((tt) + 2, bb_); \
} while (0)

#pragma unroll 1
    for (int t = 0; t < NT - 2; ++t) ITER(t, "5", true);
    ITER(NT - 2, "5", false);
    ITER(NT - 1, "0", false);
#undef ITER
#undef STAGE

    // epilogue (swapped layout): m = wm+mi*16+r (per lane), n = wn+ni*16+g*4+j
#pragma unroll
    for (int mi = 0; mi < 2; ++mi) {
        size_t m = m0 + wm + mi * 16 + r;
#pragma unroll
        for (int ni = 0; ni < 6; ++ni) {
            int nb = n0 + wn + ni * 16 + (g << 2);
            f32x4 a = acc[mi][ni];
            if constexpr (EPI == EPI_QKV) {
                us4 u;
#pragma unroll
                for (int j = 0; j < 4; ++j) {
                    __bf16 hb = (__bf16)a[j];
                    u[j] = __builtin_bit_cast(unsigned short, hb);
                }
                *(us4*)&outq[m * 1152 + nb] = u;
            } else if constexpr (EPI == EPI_FFN1) {
                f32x4 b4 = *(const f32x4*)&bias[nb];
                us4 u;
#pragma unroll
                for (int j = 0; j < 4; ++j) {
                    float z = a[j] + b4[j]; z = z > 0.f ? z : 0.f;
                    __bf16 hb = (__bf16)z;
                    u[j] = __builtin_bit_cast(unsigned short, hb);
                }
                *(us4*)&outb[m * FF + nb] = u;
            } else {
                f32x4 b4 = *(const f32x4*)&bias[nb];
                f32x4 rv = *(const f32x4*)&resid[m * 384 + nb];
                f32x4 o;
#pragma unroll
                for (int j = 0; j < 4; ++j) o[j] = rv[j] + a[j] + b4[j];
                *(f32x4*)&outf[m * 384 + nb] = o;
            }
        }
    }
}

// ---- causal attention: LDS-staged K/V, XOR-swizzled, dbuf prefetch, 1 barrier/tile
__global__ __launch_bounds__(256) void attn_k(
    const bf16* __restrict__ qkv, const bf16* __restrict__ vT,
    bf16* __restrict__ att)
{
    __shared__ bf16 Ksm[2][64][64];
    __shared__ bf16 Vsm[2][64][64];   // Vsm[buf][e][s_local]
    __shared__ bf16 Psm[4][16][72];   // 144B stride: aligned + conflict-free
    int bid = blockIdx.x;
    // XCD chunking: the 4 q-tiles of a head stay adjacent on one XCD
    int wg = (bid & 7) * 384 + (bid >> 3);
    int qt = wg & 3, bh = wg >> 2;
    int b = bh / N_HEAD, h = bh - b * N_HEAD;
    int q0 = qt * 64;
    int tid = threadIdx.x, lane = tid & 63, w = tid >> 6;
    int r = lane & 15, g = lane >> 4, ko = g << 3;
    int lr = lane >> 3, l7 = lane & 7;
    int csw = (l7 ^ lr) << 3;        // pre-swizzled source col (elements)
    int r7 = r & 7;

    const bf16* qbase = qkv + (size_t)b * T_LEN * 1152 + h * 64;
    const bf16* kbase = qbase + 384;
    const bf16* vbase = vT + (size_t)bh * HEAD * T_LEN;

    // stage K rows [s0+row0, +8) and V e-rows [row0, +8) with swizzled source
#define STAGEA(st, bb) do { \
    int s0_ = (st) * 64; \
    _Pragma("unroll") for (int s_ = 0; s_ < 2; ++s_) { \
        int row0_ = w * 16 + s_ * 8; \
        GLOAD_LDS16(kbase + (size_t)(s0_ + row0_ + lr) * 1152 + csw, &Ksm[bb][row0_][0]); \
        GLOAD_LDS16(vbase + (size_t)(row0_ + lr) * T_LEN + s0_ + csw, &Vsm[bb][row0_][0]); \
    } \
} while (0)

    STAGEA(0, 0);

    bf16x8 qf[2];
    qf[0] = *(const bf16x8*)&qbase[(size_t)(q0 + w * 16 + r) * 1152 + ko];
    qf[1] = *(const bf16x8*)&qbase[(size_t)(q0 + w * 16 + r) * 1152 + ko + 32];

    f32x4 o[4];
#pragma unroll
    for (int i = 0; i < 4; ++i) o[i] = (f32x4){0.f, 0.f, 0.f, 0.f};
    float mrow[4], lrow[4];
#pragma unroll
    for (int j = 0; j < 4; ++j) { mrow[j] = -3.0e38f; lrow[j] = 0.f; }

    for (int st = 0; st <= qt; ++st) {
        int buf = st & 1;
        __syncthreads();                 // drains vmcnt -> staged tile visible
        if (st < qt) STAGEA(st + 1, buf ^ 1);   // prefetch hides under compute

        // QK^T with swizzled LDS reads (chunk (4kk+g)^(r&7))
        f32x4 s[4];
#pragma unroll
        for (int i = 0; i < 4; ++i) s[i] = (f32x4){0.f, 0.f, 0.f, 0.f};
#pragma unroll
        for (int kk = 0; kk < 2; ++kk) {
#pragma unroll
            for (int ni = 0; ni < 4; ++ni) {
                bf16x8 kf = *(const bf16x8*)&Ksm[buf][ni * 16 + r][((4 * kk + g) ^ r7) << 3];
                s[ni] = mfma16(qf[kk], kf, s[ni]);
            }
        }
        // scale + causal mask + per-row (16-lane-group) online softmax
        int qrow = q0 + w * 16 + (g << 2);
        int s0 = st * 64;
        float tmax[4], fsc[4], tsum[4];
#pragma unroll
        for (int j = 0; j < 4; ++j) {
            float mx = -3.0e38f;
#pragma unroll
            for (int ni = 0; ni < 4; ++ni) {
                int col = s0 + ni * 16 + r;
                float sv = (col <= qrow + j) ? s[ni][j] * 0.125f : -3.0e38f;
                s[ni][j] = sv;
                mx = fmaxf(mx, sv);
            }
            tmax[j] = mx;
        }
#pragma unroll
        for (int mk = 1; mk < 16; mk <<= 1)
#pragma unroll
            for (int j = 0; j < 4; ++j) tmax[j] = fmaxf(tmax[j], __shfl_xor(tmax[j], mk));
#pragma unroll
        for (int j = 0; j < 4; ++j) {
            float mnew = fmaxf(mrow[j], tmax[j]);
            fsc[j] = __expf(mrow[j] - mnew);
            mrow[j] = mnew;
            float ss = 0.f;
#pragma unroll
            for (int ni = 0; ni < 4; ++ni) {
                float p = __expf(s[ni][j] - mnew);
                s[ni][j] = p; ss += p;
            }
            tsum[j] = ss;
        }
#pragma unroll
        for (int mk = 1; mk < 16; mk <<= 1)
#pragma unroll
            for (int j = 0; j < 4; ++j) tsum[j] += __shfl_xor(tsum[j], mk);
#pragma unroll
        for (int j = 0; j < 4; ++j) lrow[j] = lrow[j] * fsc[j] + tsum[j];
#pragma unroll
        for (int ni = 0; ni < 4; ++ni)
#pragma unroll
            for (int j = 0; j < 4; ++j) o[ni][j] *= fsc[j];
        // P -> per-wave LDS buffer (no cross-wave sharing), then PV
#pragma unroll
        for (int ni = 0; ni < 4; ++ni)
#pragma unroll
            for (int j = 0; j < 4; ++j)
                Psm[w][(g << 2) + j][ni * 16 + r] = __float2bfloat16(s[ni][j]);
#pragma unroll
        for (int kk = 0; kk < 2; ++kk) {
            bf16x8 pf = *(const bf16x8*)&Psm[w][r][kk * 32 + ko];
#pragma unroll
            for (int ni = 0; ni < 4; ++ni) {
                bf16x8 vf = *(const bf16x8*)&Vsm[buf][ni * 16 + r][((4 * kk + g) ^ r7) << 3];
                o[ni] = mfma16(pf, vf, o[ni]);
            }
        }
    }
#undef STAGEA

#pragma unroll
    for (int ni = 0; ni < 4; ++ni)
#pragma unroll
        for (int j = 0; j < 4; ++j) {
            int t = q0 + w * 16 + (g << 2) + j;
            int e = h * HEAD + ni * 16 + r;
            att[((size_t)b * T_LEN + t) * D_MODEL + e] = __float2bfloat16(o[ni][j] / lrow[j]);
        }
}

// ---------------- launch ----------------
#define GEMM_SMEM 81920

extern "C" void kernel_launch(void* const* d_in, const int* in_sizes, int n_in,
                              void* d_out, int out_size, void* d_ws, size_t ws_size,
                              hipStream_t stream)
{
    const float* x   = (const float*)d_in[0];
    const float* Wq  = (const float*)d_in[1];
    const float* Wk  = (const float*)d_in[2];
    const float* Wv  = (const float*)d_in[3];
    const float* Wp  = (const float*)d_in[4];
    const float* bp  = (const float*)d_in[5];
    const float* W1  = (const float*)d_in[6];
    const float* b1  = (const float*)d_in[7];
    const float* W2  = (const float*)d_in[8];
    const float* b2  = (const float*)d_in[9];
    const float* g1  = (const float*)d_in[10];
    const float* be1 = (const float*)d_in[11];
    const float* g2  = (const float*)d_in[12];
    const float* be2 = (const float*)d_in[13];
    float* out = (float*)d_out;

    char* ws = (char*)d_ws;
    size_t off = 0;
    auto alloc = [&](size_t bytes) { void* p = ws + off; off += (bytes + 255) & ~(size_t)255; return p; };
    bf16* Wqkv_t = (bf16*)alloc((size_t)1152 * 384 * 2);
    bf16* Wp_t   = (bf16*)alloc((size_t)384 * 384 * 2);
    bf16* W1_t   = (bf16*)alloc((size_t)1536 * 384 * 2);
    bf16* W2_t   = (bf16*)alloc((size_t)384 * 1536 * 2);
    bf16* h      = (bf16*)alloc((size_t)MROWS * 384 * 2);   // ln1 out; vT alias; ln2 out
    bf16* qkv    = (bf16*)alloc((size_t)MROWS * 1152 * 2);  // merged q|k|v
    bf16* attb   = (bf16*)alloc((size_t)MROWS * 384 * 2);
    float* x1    = (float*)alloc((size_t)MROWS * 384 * 4);
    bf16* vTb    = h;             // alias: h (ln1 out) dead after QKV gemm
    bf16* ff1    = qkv;           // alias: qkv+attb dead by FFN1; spans both

    hipFuncSetAttribute(reinterpret_cast<const void*>(&gemm8<EPI_QKV, 384, 6>),
                        hipFuncAttributeMaxDynamicSharedMemorySize, GEMM_SMEM);
    hipFuncSetAttribute(reinterpret_cast<const void*>(&gemm8<EPI_PROJ, 384, 2>),
                        hipFuncAttributeMaxDynamicSharedMemorySize, GEMM_SMEM);
    hipFuncSetAttribute(reinterpret_cast<const void*>(&gemm8<EPI_FFN1, 384, 8>),
                        hipFuncAttributeMaxDynamicSharedMemorySize, GEMM_SMEM);
    hipFuncSetAttribute(reinterpret_cast<const void*>(&gemm8<EPI_FFN2, 1536, 2>),
                        hipFuncAttributeMaxDynamicSharedMemorySize, GEMM_SMEM);

    prep_w<<<2304, 256, 0, stream>>>(Wq, Wk, Wv, Wp, W1, W2, Wqkv_t, Wp_t, W1_t, W2_t);
    ln_k<<<MROWS / 4, 256, 0, stream>>>(x, g1, be1, h);
    gemm8<EPI_QKV, 384, 6><<<1536, 512, GEMM_SMEM, stream>>>(
        h, Wqkv_t, nullptr, nullptr, nullptr, qkv, nullptr);
    tr_v<<<BATCH * N_HEAD, 256, 0, stream>>>(qkv, vTb);
    attn_k<<<BATCH * N_HEAD * 4, 256, 0, stream>>>(qkv, vTb, attb);
    gemm8<EPI_PROJ, 384, 2><<<512, 512, GEMM_SMEM, stream>>>(
        attb, Wp_t, bp, x, x1, nullptr, nullptr);
    ln_k<<<MROWS / 4, 256, 0, stream>>>(x1, g2, be2, h);
    gemm8<EPI_FFN1, 384, 8><<<2048, 512, GEMM_SMEM, stream>>>(
        h, W1_t, b1, nullptr, nullptr, nullptr, ff1);
    gemm8<EPI_FFN2, 1536, 2><<<512, 512, GEMM_SMEM, stream>>>(
        ff1, W2_t, b2, x1, out, nullptr, nullptr);
}